// Round 16
// baseline (267.440 us; speedup 1.0000x reference)
//
#include <hip/hip_runtime.h>
#include <stdint.h>

typedef unsigned short u16;
typedef __bf16 bf16x8 __attribute__((ext_vector_type(8)));
typedef short s16x4 __attribute__((ext_vector_type(4)));
typedef float f32x4 __attribute__((ext_vector_type(4)));

#define QKV_STRIDE 12288    // per (s,h): 384 * 32

__device__ __forceinline__ u16 f2bf(float x) {
    unsigned int u = __float_as_uint(x);
    u += 0x7fffu + ((u >> 16) & 1u);
    return (u16)(u >> 16);
}
__device__ __forceinline__ float bf2f(u16 h) {
    return __uint_as_float(((unsigned int)h) << 16);
}

// async global->LDS, 16B per lane; lds dest is wave-uniform base + lane*16
__device__ __forceinline__ void async_copy16(const u16* g, u16* l) {
    __builtin_amdgcn_global_load_lds(
        (const __attribute__((address_space(1))) unsigned int*)g,
        (__attribute__((address_space(3))) unsigned int*)l, 16, 0, 0);
}

// ------------------------------------------------- prep: convert msa + pack W
__global__ void prep(const float* __restrict__ msa,
                     const float* __restrict__ Wq, const float* __restrict__ Wk,
                     const float* __restrict__ Wv, const float* __restrict__ Wo,
                     u16* __restrict__ msa_bf, u16* __restrict__ Wqkv,
                     u16* __restrict__ Woh, u16* __restrict__ Wol) {
    int b = blockIdx.x;
    if (b < 12288) {
        int i = b * 256 + threadIdx.x;
        float4 v = ((const float4*)msa)[i];
        ushort4 o;
        o.x = f2bf(v.x); o.y = f2bf(v.y); o.z = f2bf(v.z); o.w = f2bf(v.w);
        ((ushort4*)msa_bf)[i] = o;
    } else {
        int i = (b - 12288) * 256 + threadIdx.x;     // 65536 total
        Wqkv[i]          = f2bf(Wq[i]);
        Wqkv[65536 + i]  = f2bf(Wk[i]);
        Wqkv[131072 + i] = f2bf(Wv[i]);
        float w = Wo[i];
        u16 hi = f2bf(w);
        Woh[i] = hi;
        Wol[i] = f2bf(w - bf2f(hi));
    }
}

// ---------------------------------------------------------------- QKV GEMM
// 3-buffer, 2-step-ahead pipeline with counted vmcnt (T4). R10 showed the
// 2-phase drain-at-barrier stalls ~LLC-latency per step and occupancy does
// NOT fix it ((256,4) regressed 48.4->53.5: all pipes idle). Here stage(t+2)
// is in flight across the barrier: per step, s_waitcnt vmcnt(4) retires the
// OLDEST 4 loads (= stage(t+1), vmcnt retires in order, m135) and leaves
// stage(t+2)'s 4 outstanding; raw s_barrier (no implicit vmcnt(0) drain)
// then publishes all waves' deposits. Buffer (t+2)%3 was last read in step
// t-1, whose readers passed that step's barrier -> no overwrite race.
// sched_barrier(0) before each wait pins the compute cluster (ds_reads +
// lgkm waits + MFMAs) ABOVE the vmcnt/s_barrier (rule #18: hipcc may sink
// register-only MFMAs past inline-asm waits).
// Control flow is wave-uniform (no divergent barriers); LDS offsets bounded.
// launch_bounds back to measured-better (256,2). LDS 48KB.
// tn<4 (Q,K): transposed orientation, packed [sh][l][d] stores (Q pre-scaled).
// tn>=4 (V): normal orientation, packed V^T [sh][d][l] stores.
__launch_bounds__(256, 2)
__global__ void qkv_gemm(const u16* __restrict__ A, const u16* __restrict__ W,
                         u16* __restrict__ Qb, u16* __restrict__ Kb, u16* __restrict__ VTb) {
    __shared__ __align__(16) u16 As[3 * 128 * 32];   // 24 KB (3 buffers)
    __shared__ __align__(16) u16 Bs[3 * 128 * 32];   // 24 KB
    const int tid = threadIdx.x;
    const int tm = blockIdx.x % 384, tn = blockIdx.x / 384;   // grid 2304
    const bool trans = (tn < 4);
    const int lane = tid & 63, wave = tid >> 6;
    const int lm = lane & 15, lq = lane >> 4;
    const int wm = (wave >> 1) * 64, wn = (wave & 1) * 64;
    const float CEXPF = 0.17677669529663687f * 1.4426950408889634f;
    f32x4 acc[4][4] = {};

    // async staging geometry: lane deposits 16B at (wave*1024 + lane*16) bytes
    const int srow = wave * 16 + (lane >> 2);
    const int scol = (lane & 3) * 8;
    const int ldso = wave * 512 + lane * 8;
    const u16* gA0 = &A[(tm * 128 + srow) * 256 + scol];
    const u16* gA1 = &A[(tm * 128 + 64 + srow) * 256 + scol];
    const u16* gB0 = &W[(tn * 128 + srow) * 256 + scol];
    const u16* gB1 = &W[(tn * 128 + 64 + srow) * 256 + scol];

    #define STAGE(t, b) do {                                      \
        const int _k = (t) * 32, _o = (b) * 4096 + ldso;          \
        async_copy16(gA0 + _k, &As[_o]);                          \
        async_copy16(gA1 + _k, &As[_o + 2048]);                   \
        async_copy16(gB0 + _k, &Bs[_o]);                          \
        async_copy16(gB1 + _k, &Bs[_o + 2048]);                   \
    } while (0)

    // prologue: 2 tiles in flight, wait for the oldest
    STAGE(0, 0);
    STAGE(1, 1);
    __builtin_amdgcn_sched_barrier(0);
    asm volatile("s_waitcnt vmcnt(4)" ::: "memory");   // buf0 landed
    __builtin_amdgcn_s_barrier();

    #pragma unroll
    for (int t = 0; t < 8; ++t) {
        if (t < 6) STAGE(t + 2, (t + 2) % 3);
        __builtin_amdgcn_sched_barrier(0);             // pin stage-issues above compute
        const int p = (t % 3) * 4096;
        const u16* Xs = trans ? &Bs[p] : &As[p];   // A-operand (m dim)
        const u16* Ys = trans ? &As[p] : &Bs[p];   // B-operand (n dim)
        bf16x8 xf[4], yf[4];
        #pragma unroll
        for (int i = 0; i < 4; ++i)
            xf[i] = *(const bf16x8*)&Xs[(wm + i * 16 + lm) * 32 + lq * 8];
        #pragma unroll
        for (int j = 0; j < 4; ++j)
            yf[j] = *(const bf16x8*)&Ys[(wn + j * 16 + lm) * 32 + lq * 8];
        #pragma unroll
        for (int i = 0; i < 4; ++i)
            #pragma unroll
            for (int j = 0; j < 4; ++j)
                acc[i][j] = __builtin_amdgcn_mfma_f32_16x16x32_bf16(xf[i], yf[j], acc[i][j], 0, 0, 0);
        if (t < 6) {
            __builtin_amdgcn_sched_barrier(0);         // keep compute (ds_reads+MFMAs) above the wait
            asm volatile("s_waitcnt vmcnt(4)" ::: "memory");  // stage(t+1) done, stage(t+2) in flight
            __builtin_amdgcn_s_barrier();
        } else if (t == 6) {
            __builtin_amdgcn_sched_barrier(0);
            asm volatile("s_waitcnt vmcnt(0)" ::: "memory");  // stage(7) done
            __builtin_amdgcn_s_barrier();
        }
    }
    #undef STAGE

    if (trans) {
        // m = feature F (r -> d contiguous), n = msa row R
        #pragma unroll
        for (int i = 0; i < 4; ++i) {
            int F0 = tn * 128 + wm + i * 16 + lq * 4;
            int which = F0 >> 8;                 // 0=Q, 1=K
            int h = (F0 >> 5) & 7, d0 = F0 & 31;
            u16* dst = which ? Kb : Qb;
            float scale = which ? 1.0f : CEXPF;
            #pragma unroll
            for (int j = 0; j < 4; ++j) {
                int R = tm * 128 + wn + j * 16 + lm;
                int s = R / 384, l = R - s * 384;
                ushort4 o;
                o.x = f2bf(acc[i][j][0] * scale);
                o.y = f2bf(acc[i][j][1] * scale);
                o.z = f2bf(acc[i][j][2] * scale);
                o.w = f2bf(acc[i][j][3] * scale);
                *(ushort4*)&dst[((s * 8 + h) * 384 + l) * 32 + d0] = o;
            }
        }
    } else {
        // m = msa row R (r -> l contiguous), n = feature F in [512,768)
        #pragma unroll
        for (int j = 0; j < 4; ++j) {
            int F = tn * 128 + wn + j * 16 + lm;
            int h = (F >> 5) & 7, d = F & 31;
            #pragma unroll
            for (int i = 0; i < 4; ++i) {
                int R0 = tm * 128 + wm + i * 16 + lq * 4;
                int s = R0 / 384, l0 = R0 - s * 384;
                ushort4 o;
                o.x = f2bf(acc[i][j][0]);
                o.y = f2bf(acc[i][j][1]);
                o.z = f2bf(acc[i][j][2]);
                o.w = f2bf(acc[i][j][3]);
                *(ushort4*)&VTb[((s * 8 + h) * 32 + d) * 384 + l0] = o;
            }
        }
    }
}

// ---------------------------------------------------------------- attention
// Grid 3072. XCD-aware remap (R10: helped, left top-5 — kept):
//   xcd = bid&7, j = bid>>3, sh = xcd*128 + j/3, lpart = j%3   (bijective)
// -> the 3 lparts of each sh run adjacently on one XCD; K,V fetched once per
// L2. PV runs as K=32 16x16x32 MFMAs (two K=16 QK C-frag slices concat as one
// B-frag; two V^T k-slices concat as one A-frag; both sides use the same
// (lq,elem)->n bijection). l = 1^T*P via a ones-MFMA.
__launch_bounds__(256, 6)
__global__ void msa_attention(const u16* __restrict__ Qb, const u16* __restrict__ Kb,
                              const u16* __restrict__ VTb,
                              u16* __restrict__ Ahi, u16* __restrict__ Alo) {
    __shared__ __align__(16) u16 Vt[32 * 392];   // 25088 B (V^T rows, stride 392)
    const int tid = threadIdx.x;
    const int bid = blockIdx.x;                   // 3072 blocks
    const int xcd = bid & 7, j = bid >> 3;        // j in [0,384)
    const int jd3 = j / 3;
    const int sh = xcd * 128 + jd3, lpart = j - jd3 * 3;
    const int s = sh >> 3, h = sh & 7;
    const u16* Qg = Qb + (size_t)sh * QKV_STRIDE;
    const u16* Kg = Kb + (size_t)sh * QKV_STRIDE;
    const u16* Vg = VTb + (size_t)sh * QKV_STRIDE;

    for (int i = tid; i < 1536; i += 256) {
        int d = i / 48, c = i - d * 48;
        *(uint4*)&Vt[d * 392 + c * 8] = *(const uint4*)&Vg[d * 384 + c * 8];
    }

    const int lane = tid & 63, wave = tid >> 6;
    const int lm = lane & 15, lq = lane >> 4;

    bf16x8 aq[2];
    #pragma unroll
    for (int it = 0; it < 2; ++it) {
        int l = lpart * 128 + (wave * 2 + it) * 16 + lm;
        aq[it] = *(const bf16x8*)&Qg[l * 32 + lq * 8];
    }
    __syncthreads();

    f32x4 o[2][2] = {};
    f32x4 lacc[2] = {};
    union pack8 { s16x4 h[2]; bf16x8 v; };
    pack8 ones8;
    {
        s16x4 one4 = {(short)0x3F80, (short)0x3F80, (short)0x3F80, (short)0x3F80};
        ones8.h[0] = one4; ones8.h[1] = one4;
    }

    for (int n0 = 0; n0 < 384; n0 += 32) {
        bf16x8 kf0 = *(const bf16x8*)&Kg[(n0 + lm) * 32 + lq * 8];
        bf16x8 kf1 = *(const bf16x8*)&Kg[(n0 + 16 + lm) * 32 + lq * 8];
        pack8 va0, va1;
        va0.h[0] = *(const s16x4*)&Vt[lm * 392 + n0 + lq * 4];
        va0.h[1] = *(const s16x4*)&Vt[lm * 392 + n0 + 16 + lq * 4];
        va1.h[0] = *(const s16x4*)&Vt[(16 + lm) * 392 + n0 + lq * 4];
        va1.h[1] = *(const s16x4*)&Vt[(16 + lm) * 392 + n0 + 16 + lq * 4];
        #pragma unroll
        for (int it = 0; it < 2; ++it) {
            f32x4 z = {0.f, 0.f, 0.f, 0.f};
            f32x4 s0 = __builtin_amdgcn_mfma_f32_16x16x32_bf16(kf0, aq[it], z, 0, 0, 0);
            f32x4 s1 = __builtin_amdgcn_mfma_f32_16x16x32_bf16(kf1, aq[it], z, 0, 0, 0);
            float p0[4], p1[4];
            #pragma unroll
            for (int r = 0; r < 4; ++r) {
                p0[r] = __builtin_amdgcn_exp2f(s0[r]);
                p1[r] = __builtin_amdgcn_exp2f(s1[r]);
            }
            pack8 pb;
            union { s16x4 v; uint2 u; } pk0, pk1;
            pk0.u.x = __builtin_amdgcn_perm(__float_as_uint(p0[1]), __float_as_uint(p0[0]), 0x07060302u);
            pk0.u.y = __builtin_amdgcn_perm(__float_as_uint(p0[3]), __float_as_uint(p0[2]), 0x07060302u);
            pk1.u.x = __builtin_amdgcn_perm(__float_as_uint(p1[1]), __float_as_uint(p1[0]), 0x07060302u);
            pk1.u.y = __builtin_amdgcn_perm(__float_as_uint(p1[3]), __float_as_uint(p1[2]), 0x07060302u);
            pb.h[0] = pk0.v; pb.h[1] = pk1.v;
            o[it][0] = __builtin_amdgcn_mfma_f32_16x16x32_bf16(va0.v, pb.v, o[it][0], 0, 0, 0);
            o[it][1] = __builtin_amdgcn_mfma_f32_16x16x32_bf16(va1.v, pb.v, o[it][1], 0, 0, 0);
            lacc[it] = __builtin_amdgcn_mfma_f32_16x16x32_bf16(ones8.v, pb.v, lacc[it], 0, 0, 0);
        }
    }

    #pragma unroll
    for (int it = 0; it < 2; ++it) {
        float inv = __builtin_amdgcn_rcpf(lacc[it][0]);
        int l = lpart * 128 + (wave * 2 + it) * 16 + lm;
        int base = (s * 384 + l) * 256 + h * 32 + lq * 4;
        #pragma unroll
        for (int dt = 0; dt < 2; ++dt) {
            ushort4 oh, ol;
            float x0 = o[it][dt][0] * inv, x1 = o[it][dt][1] * inv;
            float x2 = o[it][dt][2] * inv, x3 = o[it][dt][3] * inv;
            oh.x = f2bf(x0); ol.x = f2bf(x0 - bf2f(oh.x));
            oh.y = f2bf(x1); ol.y = f2bf(x1 - bf2f(oh.y));
            oh.z = f2bf(x2); ol.z = f2bf(x2 - bf2f(oh.z));
            oh.w = f2bf(x3); ol.w = f2bf(x3 - bf2f(oh.w));
            *(ushort4*)&Ahi[base + dt * 16] = oh;
            *(ushort4*)&Alo[base + dt * 16] = ol;
        }
    }
}

// ---------------------------------------------------------------- output GEMM
// 2-phase double-buffered (unchanged; not in top-5). LDS 64 KB ->
// 2 blocks/CU. Transposed orientation: out^T tiles, r -> feature contiguous
// -> float4 stores.
__launch_bounds__(256, 2)
__global__ void out_gemm(const u16* __restrict__ Ahi, const u16* __restrict__ Alo,
                         const u16* __restrict__ Woh, const u16* __restrict__ Wol,
                         float* __restrict__ out) {
    __shared__ __align__(16) u16 Ah[2 * 128 * 32], Al[2 * 128 * 32];
    __shared__ __align__(16) u16 Bh[2 * 128 * 32], Bl[2 * 128 * 32];
    const int tid = threadIdx.x;
    const int tm = blockIdx.x % 384, tn = blockIdx.x / 384;   // grid 768, tn in {0,1}
    const int lane = tid & 63, wave = tid >> 6;
    const int lm = lane & 15, lq = lane >> 4;
    const int wm = (wave >> 1) * 64, wn = (wave & 1) * 64;
    f32x4 acc[4][4] = {};

    const int srow = wave * 16 + (lane >> 2);
    const int scol = (lane & 3) * 8;
    const int lo0 = wave * 512 + lane * 8, lo1 = 2048 + wave * 512 + lane * 8;
    const u16* gAh0 = &Ahi[(tm * 128 + srow) * 256 + scol];
    const u16* gAh1 = &Ahi[(tm * 128 + 64 + srow) * 256 + scol];
    const u16* gAl0 = &Alo[(tm * 128 + srow) * 256 + scol];
    const u16* gAl1 = &Alo[(tm * 128 + 64 + srow) * 256 + scol];
    const u16* gBh0 = &Woh[(tn * 128 + srow) * 256 + scol];
    const u16* gBh1 = &Woh[(tn * 128 + 64 + srow) * 256 + scol];
    const u16* gBl0 = &Wol[(tn * 128 + srow) * 256 + scol];
    const u16* gBl1 = &Wol[(tn * 128 + 64 + srow) * 256 + scol];

    // prologue: stage tile 0 into buffer 0
    async_copy16(gAh0, &Ah[lo0]);
    async_copy16(gAh1, &Ah[lo1]);
    async_copy16(gAl0, &Al[lo0]);
    async_copy16(gAl1, &Al[lo1]);
    async_copy16(gBh0, &Bh[lo0]);
    async_copy16(gBh1, &Bh[lo1]);
    async_copy16(gBl0, &Bl[lo0]);
    async_copy16(gBl1, &Bl[lo1]);
    __syncthreads();

    #pragma unroll
    for (int t = 0; t < 8; ++t) {
        const int p = (t & 1) * 4096;
        if (t < 7) {
            const int pn = ((t + 1) & 1) * 4096;
            const int k1 = (t + 1) * 32;
            async_copy16(gAh0 + k1, &Ah[pn + lo0]);
            async_copy16(gAh1 + k1, &Ah[pn + lo1]);
            async_copy16(gAl0 + k1, &Al[pn + lo0]);
            async_copy16(gAl1 + k1, &Al[pn + lo1]);
            async_copy16(gBh0 + k1, &Bh[pn + lo0]);
            async_copy16(gBh1 + k1, &Bh[pn + lo1]);
            async_copy16(gBl0 + k1, &Bl[pn + lo0]);
            async_copy16(gBl1 + k1, &Bl[pn + lo1]);
        }
        bf16x8 whf[4], wlf[4], ahf[4], alf[4];
        #pragma unroll
        for (int i = 0; i < 4; ++i) {
            whf[i] = *(const bf16x8*)&Bh[p + (wm + i * 16 + lm) * 32 + lq * 8];
            wlf[i] = *(const bf16x8*)&Bl[p + (wm + i * 16 + lm) * 32 + lq * 8];
        }
        #pragma unroll
        for (int j = 0; j < 4; ++j) {
            ahf[j] = *(const bf16x8*)&Ah[p + (wn + j * 16 + lm) * 32 + lq * 8];
            alf[j] = *(const bf16x8*)&Al[p + (wn + j * 16 + lm) * 32 + lq * 8];
        }
        #pragma unroll
        for (int i = 0; i < 4; ++i)
            #pragma unroll
            for (int j = 0; j < 4; ++j) {
                acc[i][j] = __builtin_amdgcn_mfma_f32_16x16x32_bf16(whf[i], alf[j], acc[i][j], 0, 0, 0);
                acc[i][j] = __builtin_amdgcn_mfma_f32_16x16x32_bf16(wlf[i], ahf[j], acc[i][j], 0, 0, 0);
                acc[i][j] = __builtin_amdgcn_mfma_f32_16x16x32_bf16(whf[i], ahf[j], acc[i][j], 0, 0, 0);
            }
        if (t < 7) __syncthreads();
    }
    #pragma unroll
    for (int i = 0; i < 4; ++i) {
        int F0 = tn * 128 + wm + i * 16 + lq * 4;
        #pragma unroll
        for (int j = 0; j < 4; ++j) {
            int R = tm * 128 + wn + j * 16 + lm;
            *(f32x4*)&out[R * 256 + F0] = acc[i][j];
        }
    }
}

// ---------------------------------------------------------------- launch
extern "C" void kernel_launch(void* const* d_in, const int* in_sizes, int n_in,
                              void* d_out, int out_size, void* d_ws, size_t ws_size,
                              hipStream_t stream) {
    const float* msa = (const float*)d_in[0];
    const float* Wq = (const float*)d_in[2];
    const float* Wk = (const float*)d_in[3];
    const float* Wv = (const float*)d_in[4];
    const float* Wo = (const float*)d_in[5];
    char* ws = (char*)d_ws;
    u16* msa_bf = (u16*)(ws + 0);              // 25165824 B
    u16* Qb     = (u16*)(ws + 25165824);       // 25165824 B  [sh][l][d], pre-scaled
    u16* Kb     = (u16*)(ws + 50331648);       // 25165824 B  [sh][l][d]
    u16* VTb    = (u16*)(ws + 75497472);       // 25165824 B  [sh][d][l]
    u16* Ahi    = (u16*)(ws + 100663296);      // 25165824 B
    u16* Alo    = (u16*)(ws + 125829120);      // 25165824 B
    u16* Wqkv   = (u16*)(ws + 150994944);      // 393216 B
    u16* Woh    = (u16*)(ws + 151388160);      // 131072 B
    u16* Wol    = (u16*)(ws + 151519232);      // 131072 B
    float* out  = (float*)d_out;

    hipLaunchKernelGGL(prep, dim3(12544), dim3(256), 0, stream, msa, Wq, Wk, Wv, Wo,
                       msa_bf, Wqkv, Woh, Wol);
    hipLaunchKernelGGL(qkv_gemm, dim3(2304), dim3(256), 0, stream, msa_bf, Wqkv, Qb, Kb, VTb);
    hipLaunchKernelGGL(msa_attention, dim3(3072), dim3(256), 0, stream, Qb, Kb, VTb, Ahi, Alo);
    hipLaunchKernelGGL(out_gemm, dim3(768), dim3(256), 0, stream, Ahi, Alo, Woh, Wol, out);
}

// Round 19
// 245.146 us; speedup vs baseline: 1.0909x; 1.0909x over previous
//
#include <hip/hip_runtime.h>
#include <stdint.h>

typedef unsigned short u16;
typedef __bf16 bf16x8 __attribute__((ext_vector_type(8)));
typedef short s16x4 __attribute__((ext_vector_type(4)));
typedef float f32x4 __attribute__((ext_vector_type(4)));

#define QKV_STRIDE 12288    // per (s,h): 384 * 32

__device__ __forceinline__ u16 f2bf(float x) {
    unsigned int u = __float_as_uint(x);
    u += 0x7fffu + ((u >> 16) & 1u);
    return (u16)(u >> 16);
}
__device__ __forceinline__ float bf2f(u16 h) {
    return __uint_as_float(((unsigned int)h) << 16);
}

// async global->LDS, 16B per lane; lds dest is wave-uniform base + lane*16
__device__ __forceinline__ void async_copy16(const u16* g, u16* l) {
    __builtin_amdgcn_global_load_lds(
        (const __attribute__((address_space(1))) unsigned int*)g,
        (__attribute__((address_space(3))) unsigned int*)l, 16, 0, 0);
}

// ------------------------------------------------- prep: convert msa + pack W
__global__ void prep(const float* __restrict__ msa,
                     const float* __restrict__ Wq, const float* __restrict__ Wk,
                     const float* __restrict__ Wv, const float* __restrict__ Wo,
                     u16* __restrict__ msa_bf, u16* __restrict__ Wqkv,
                     u16* __restrict__ Woh, u16* __restrict__ Wol) {
    int b = blockIdx.x;
    if (b < 12288) {
        int i = b * 256 + threadIdx.x;
        float4 v = ((const float4*)msa)[i];
        ushort4 o;
        o.x = f2bf(v.x); o.y = f2bf(v.y); o.z = f2bf(v.z); o.w = f2bf(v.w);
        ((ushort4*)msa_bf)[i] = o;
    } else {
        int i = (b - 12288) * 256 + threadIdx.x;     // 65536 total
        Wqkv[i]          = f2bf(Wq[i]);
        Wqkv[65536 + i]  = f2bf(Wk[i]);
        Wqkv[131072 + i] = f2bf(Wv[i]);
        float w = Wo[i];
        u16 hi = f2bf(w);
        Woh[i] = hi;
        Wol[i] = f2bf(w - bf2f(hi));
    }
}

// ---------------------------------------------------------------- QKV GEMM
// 3-buffer, 2-step-ahead pipeline with counted vmcnt (R16: measured 47.3us,
// passed; marginally better than 2-phase 48.4. Counted-vmcnt = NULL vs
// 2-phase -> drain was not the stall; structure kept as best-measured).
// tn<4 (Q,K): transposed orientation, packed [sh][l][d] stores (Q pre-scaled).
// tn>=4 (V): normal orientation, packed V^T [sh][d][l] stores.
__launch_bounds__(256, 2)
__global__ void qkv_gemm(const u16* __restrict__ A, const u16* __restrict__ W,
                         u16* __restrict__ Qb, u16* __restrict__ Kb, u16* __restrict__ VTb) {
    __shared__ __align__(16) u16 As[3 * 128 * 32];   // 24 KB (3 buffers)
    __shared__ __align__(16) u16 Bs[3 * 128 * 32];   // 24 KB
    const int tid = threadIdx.x;
    const int tm = blockIdx.x % 384, tn = blockIdx.x / 384;   // grid 2304
    const bool trans = (tn < 4);
    const int lane = tid & 63, wave = tid >> 6;
    const int lm = lane & 15, lq = lane >> 4;
    const int wm = (wave >> 1) * 64, wn = (wave & 1) * 64;
    const float CEXPF = 0.17677669529663687f * 1.4426950408889634f;
    f32x4 acc[4][4] = {};

    // async staging geometry: lane deposits 16B at (wave*1024 + lane*16) bytes
    const int srow = wave * 16 + (lane >> 2);
    const int scol = (lane & 3) * 8;
    const int ldso = wave * 512 + lane * 8;
    const u16* gA0 = &A[(tm * 128 + srow) * 256 + scol];
    const u16* gA1 = &A[(tm * 128 + 64 + srow) * 256 + scol];
    const u16* gB0 = &W[(tn * 128 + srow) * 256 + scol];
    const u16* gB1 = &W[(tn * 128 + 64 + srow) * 256 + scol];

    #define STAGE(t, b) do {                                      \
        const int _k = (t) * 32, _o = (b) * 4096 + ldso;          \
        async_copy16(gA0 + _k, &As[_o]);                          \
        async_copy16(gA1 + _k, &As[_o + 2048]);                   \
        async_copy16(gB0 + _k, &Bs[_o]);                          \
        async_copy16(gB1 + _k, &Bs[_o + 2048]);                   \
    } while (0)

    // prologue: 2 tiles in flight, wait for the oldest
    STAGE(0, 0);
    STAGE(1, 1);
    __builtin_amdgcn_sched_barrier(0);
    asm volatile("s_waitcnt vmcnt(4)" ::: "memory");   // buf0 landed
    __builtin_amdgcn_s_barrier();

    #pragma unroll
    for (int t = 0; t < 8; ++t) {
        if (t < 6) STAGE(t + 2, (t + 2) % 3);
        __builtin_amdgcn_sched_barrier(0);             // pin stage-issues above compute
        const int p = (t % 3) * 4096;
        const u16* Xs = trans ? &Bs[p] : &As[p];   // A-operand (m dim)
        const u16* Ys = trans ? &As[p] : &Bs[p];   // B-operand (n dim)
        bf16x8 xf[4], yf[4];
        #pragma unroll
        for (int i = 0; i < 4; ++i)
            xf[i] = *(const bf16x8*)&Xs[(wm + i * 16 + lm) * 32 + lq * 8];
        #pragma unroll
        for (int j = 0; j < 4; ++j)
            yf[j] = *(const bf16x8*)&Ys[(wn + j * 16 + lm) * 32 + lq * 8];
        #pragma unroll
        for (int i = 0; i < 4; ++i)
            #pragma unroll
            for (int j = 0; j < 4; ++j)
                acc[i][j] = __builtin_amdgcn_mfma_f32_16x16x32_bf16(xf[i], yf[j], acc[i][j], 0, 0, 0);
        if (t < 6) {
            __builtin_amdgcn_sched_barrier(0);         // keep compute above the wait
            asm volatile("s_waitcnt vmcnt(4)" ::: "memory");  // stage(t+1) done, stage(t+2) in flight
            __builtin_amdgcn_s_barrier();
        } else if (t == 6) {
            __builtin_amdgcn_sched_barrier(0);
            asm volatile("s_waitcnt vmcnt(0)" ::: "memory");  // stage(7) done
            __builtin_amdgcn_s_barrier();
        }
    }
    #undef STAGE

    if (trans) {
        // m = feature F (r -> d contiguous), n = msa row R
        #pragma unroll
        for (int i = 0; i < 4; ++i) {
            int F0 = tn * 128 + wm + i * 16 + lq * 4;
            int which = F0 >> 8;                 // 0=Q, 1=K
            int h = (F0 >> 5) & 7, d0 = F0 & 31;
            u16* dst = which ? Kb : Qb;
            float scale = which ? 1.0f : CEXPF;
            #pragma unroll
            for (int j = 0; j < 4; ++j) {
                int R = tm * 128 + wn + j * 16 + lm;
                int s = R / 384, l = R - s * 384;
                ushort4 o;
                o.x = f2bf(acc[i][j][0] * scale);
                o.y = f2bf(acc[i][j][1] * scale);
                o.z = f2bf(acc[i][j][2] * scale);
                o.w = f2bf(acc[i][j][3] * scale);
                *(ushort4*)&dst[((s * 8 + h) * 384 + l) * 32 + d0] = o;
            }
        }
    } else {
        // m = msa row R (r -> l contiguous), n = feature F in [512,768)
        #pragma unroll
        for (int j = 0; j < 4; ++j) {
            int F = tn * 128 + wn + j * 16 + lm;
            int h = (F >> 5) & 7, d = F & 31;
            #pragma unroll
            for (int i = 0; i < 4; ++i) {
                int R0 = tm * 128 + wm + i * 16 + lq * 4;
                int s = R0 / 384, l0 = R0 - s * 384;
                ushort4 o;
                o.x = f2bf(acc[i][j][0]);
                o.y = f2bf(acc[i][j][1]);
                o.z = f2bf(acc[i][j][2]);
                o.w = f2bf(acc[i][j][3]);
                *(ushort4*)&VTb[((s * 8 + h) * 32 + d) * 384 + l0] = o;
            }
        }
    }
}

// ---------------------------------------------------------------- attention
// Grid 3072. XCD-aware remap (R10: helped — kept). PV as K=32 MFMAs; ones-row
// l-sum. CHANGE (R17): output A written as SINGLE bf16 (Ahi only) — the Alo
// low-half is dropped. Error analysis: |A|<~0.32, bf16 abs err <= 6e-4/elem,
// through 256-dot with Wo~0.02 -> adds ~2e-4 absmax (current 1.2e-4).
// Saves 25MB write here + 25MB read in out_gemm (pipeline is ~2.5TB/s
// traffic-bound per R8/R16 counters).
__launch_bounds__(256, 6)
__global__ void msa_attention(const u16* __restrict__ Qb, const u16* __restrict__ Kb,
                              const u16* __restrict__ VTb,
                              u16* __restrict__ Ahi) {
    __shared__ __align__(16) u16 Vt[32 * 392];   // 25088 B (V^T rows, stride 392)
    const int tid = threadIdx.x;
    const int bid = blockIdx.x;                   // 3072 blocks
    const int xcd = bid & 7, j = bid >> 3;        // j in [0,384)
    const int jd3 = j / 3;
    const int sh = xcd * 128 + jd3, lpart = j - jd3 * 3;
    const int s = sh >> 3, h = sh & 7;
    const u16* Qg = Qb + (size_t)sh * QKV_STRIDE;
    const u16* Kg = Kb + (size_t)sh * QKV_STRIDE;
    const u16* Vg = VTb + (size_t)sh * QKV_STRIDE;

    for (int i = tid; i < 1536; i += 256) {
        int d = i / 48, c = i - d * 48;
        *(uint4*)&Vt[d * 392 + c * 8] = *(const uint4*)&Vg[d * 384 + c * 8];
    }

    const int lane = tid & 63, wave = tid >> 6;
    const int lm = lane & 15, lq = lane >> 4;

    bf16x8 aq[2];
    #pragma unroll
    for (int it = 0; it < 2; ++it) {
        int l = lpart * 128 + (wave * 2 + it) * 16 + lm;
        aq[it] = *(const bf16x8*)&Qg[l * 32 + lq * 8];
    }
    __syncthreads();

    f32x4 o[2][2] = {};
    f32x4 lacc[2] = {};
    union pack8 { s16x4 h[2]; bf16x8 v; };
    pack8 ones8;
    {
        s16x4 one4 = {(short)0x3F80, (short)0x3F80, (short)0x3F80, (short)0x3F80};
        ones8.h[0] = one4; ones8.h[1] = one4;
    }

    for (int n0 = 0; n0 < 384; n0 += 32) {
        bf16x8 kf0 = *(const bf16x8*)&Kg[(n0 + lm) * 32 + lq * 8];
        bf16x8 kf1 = *(const bf16x8*)&Kg[(n0 + 16 + lm) * 32 + lq * 8];
        pack8 va0, va1;
        va0.h[0] = *(const s16x4*)&Vt[lm * 392 + n0 + lq * 4];
        va0.h[1] = *(const s16x4*)&Vt[lm * 392 + n0 + 16 + lq * 4];
        va1.h[0] = *(const s16x4*)&Vt[(16 + lm) * 392 + n0 + lq * 4];
        va1.h[1] = *(const s16x4*)&Vt[(16 + lm) * 392 + n0 + 16 + lq * 4];
        #pragma unroll
        for (int it = 0; it < 2; ++it) {
            f32x4 z = {0.f, 0.f, 0.f, 0.f};
            f32x4 s0 = __builtin_amdgcn_mfma_f32_16x16x32_bf16(kf0, aq[it], z, 0, 0, 0);
            f32x4 s1 = __builtin_amdgcn_mfma_f32_16x16x32_bf16(kf1, aq[it], z, 0, 0, 0);
            float p0[4], p1[4];
            #pragma unroll
            for (int r = 0; r < 4; ++r) {
                p0[r] = __builtin_amdgcn_exp2f(s0[r]);
                p1[r] = __builtin_amdgcn_exp2f(s1[r]);
            }
            pack8 pb;
            union { s16x4 v; uint2 u; } pk0, pk1;
            pk0.u.x = __builtin_amdgcn_perm(__float_as_uint(p0[1]), __float_as_uint(p0[0]), 0x07060302u);
            pk0.u.y = __builtin_amdgcn_perm(__float_as_uint(p0[3]), __float_as_uint(p0[2]), 0x07060302u);
            pk1.u.x = __builtin_amdgcn_perm(__float_as_uint(p1[1]), __float_as_uint(p1[0]), 0x07060302u);
            pk1.u.y = __builtin_amdgcn_perm(__float_as_uint(p1[3]), __float_as_uint(p1[2]), 0x07060302u);
            pb.h[0] = pk0.v; pb.h[1] = pk1.v;
            o[it][0] = __builtin_amdgcn_mfma_f32_16x16x32_bf16(va0.v, pb.v, o[it][0], 0, 0, 0);
            o[it][1] = __builtin_amdgcn_mfma_f32_16x16x32_bf16(va1.v, pb.v, o[it][1], 0, 0, 0);
            lacc[it] = __builtin_amdgcn_mfma_f32_16x16x32_bf16(ones8.v, pb.v, lacc[it], 0, 0, 0);
        }
    }

    #pragma unroll
    for (int it = 0; it < 2; ++it) {
        float inv = __builtin_amdgcn_rcpf(lacc[it][0]);
        int l = lpart * 128 + (wave * 2 + it) * 16 + lm;
        int base = (s * 384 + l) * 256 + h * 32 + lq * 4;
        #pragma unroll
        for (int dt = 0; dt < 2; ++dt) {
            ushort4 oh;
            oh.x = f2bf(o[it][dt][0] * inv);
            oh.y = f2bf(o[it][dt][1] * inv);
            oh.z = f2bf(o[it][dt][2] * inv);
            oh.w = f2bf(o[it][dt][3] * inv);
            *(ushort4*)&Ahi[base + dt * 16] = oh;
        }
    }
}

// ---------------------------------------------------------------- output GEMM
// 2-phase double-buffered. CHANGE (R17): A is single-bf16 now -> 3 LDS arrays
// (Ah, Bh, Bl = 48KB), 2 MFMAs per ij: (Wh + Wl) x A. W keeps hi/lo.
// Transposed orientation: out^T tiles, r -> feature contiguous -> f32x4 stores.
__launch_bounds__(256, 2)
__global__ void out_gemm(const u16* __restrict__ Ahi,
                         const u16* __restrict__ Woh, const u16* __restrict__ Wol,
                         float* __restrict__ out) {
    __shared__ __align__(16) u16 Ah[2 * 128 * 32];
    __shared__ __align__(16) u16 Bh[2 * 128 * 32], Bl[2 * 128 * 32];
    const int tid = threadIdx.x;
    const int tm = blockIdx.x % 384, tn = blockIdx.x / 384;   // grid 768, tn in {0,1}
    const int lane = tid & 63, wave = tid >> 6;
    const int lm = lane & 15, lq = lane >> 4;
    const int wm = (wave >> 1) * 64, wn = (wave & 1) * 64;
    f32x4 acc[4][4] = {};

    const int srow = wave * 16 + (lane >> 2);
    const int scol = (lane & 3) * 8;
    const int lo0 = wave * 512 + lane * 8, lo1 = 2048 + wave * 512 + lane * 8;
    const u16* gAh0 = &Ahi[(tm * 128 + srow) * 256 + scol];
    const u16* gAh1 = &Ahi[(tm * 128 + 64 + srow) * 256 + scol];
    const u16* gBh0 = &Woh[(tn * 128 + srow) * 256 + scol];
    const u16* gBh1 = &Woh[(tn * 128 + 64 + srow) * 256 + scol];
    const u16* gBl0 = &Wol[(tn * 128 + srow) * 256 + scol];
    const u16* gBl1 = &Wol[(tn * 128 + 64 + srow) * 256 + scol];

    // prologue: stage tile 0 into buffer 0
    async_copy16(gAh0, &Ah[lo0]);
    async_copy16(gAh1, &Ah[lo1]);
    async_copy16(gBh0, &Bh[lo0]);
    async_copy16(gBh1, &Bh[lo1]);
    async_copy16(gBl0, &Bl[lo0]);
    async_copy16(gBl1, &Bl[lo1]);
    __syncthreads();

    #pragma unroll
    for (int t = 0; t < 8; ++t) {
        const int p = (t & 1) * 4096;
        if (t < 7) {
            const int pn = ((t + 1) & 1) * 4096;
            const int k1 = (t + 1) * 32;
            async_copy16(gAh0 + k1, &Ah[pn + lo0]);
            async_copy16(gAh1 + k1, &Ah[pn + lo1]);
            async_copy16(gBh0 + k1, &Bh[pn + lo0]);
            async_copy16(gBh1 + k1, &Bh[pn + lo1]);
            async_copy16(gBl0 + k1, &Bl[pn + lo0]);
            async_copy16(gBl1 + k1, &Bl[pn + lo1]);
        }
        bf16x8 whf[4], wlf[4], ahf[4];
        #pragma unroll
        for (int i = 0; i < 4; ++i) {
            whf[i] = *(const bf16x8*)&Bh[p + (wm + i * 16 + lm) * 32 + lq * 8];
            wlf[i] = *(const bf16x8*)&Bl[p + (wm + i * 16 + lm) * 32 + lq * 8];
        }
        #pragma unroll
        for (int j = 0; j < 4; ++j)
            ahf[j] = *(const bf16x8*)&Ah[p + (wn + j * 16 + lm) * 32 + lq * 8];
        #pragma unroll
        for (int i = 0; i < 4; ++i)
            #pragma unroll
            for (int j = 0; j < 4; ++j) {
                acc[i][j] = __builtin_amdgcn_mfma_f32_16x16x32_bf16(whf[i], ahf[j], acc[i][j], 0, 0, 0);
                acc[i][j] = __builtin_amdgcn_mfma_f32_16x16x32_bf16(wlf[i], ahf[j], acc[i][j], 0, 0, 0);
            }
        if (t < 7) __syncthreads();
    }
    #pragma unroll
    for (int i = 0; i < 4; ++i) {
        int F0 = tn * 128 + wm + i * 16 + lq * 4;
        #pragma unroll
        for (int j = 0; j < 4; ++j) {
            int R = tm * 128 + wn + j * 16 + lm;
            *(f32x4*)&out[R * 256 + F0] = acc[i][j];
        }
    }
}

// ---------------------------------------------------------------- launch
extern "C" void kernel_launch(void* const* d_in, const int* in_sizes, int n_in,
                              void* d_out, int out_size, void* d_ws, size_t ws_size,
                              hipStream_t stream) {
    const float* msa = (const float*)d_in[0];
    const float* Wq = (const float*)d_in[2];
    const float* Wk = (const float*)d_in[3];
    const float* Wv = (const float*)d_in[4];
    const float* Wo = (const float*)d_in[5];
    char* ws = (char*)d_ws;
    u16* msa_bf = (u16*)(ws + 0);              // 25165824 B
    u16* Qb     = (u16*)(ws + 25165824);       // 25165824 B  [sh][l][d], pre-scaled
    u16* Kb     = (u16*)(ws + 50331648);       // 25165824 B  [sh][l][d]
    u16* VTb    = (u16*)(ws + 75497472);       // 25165824 B  [sh][d][l]
    u16* Ahi    = (u16*)(ws + 100663296);      // 25165824 B
    u16* Wqkv   = (u16*)(ws + 150994944);      // 393216 B
    u16* Woh    = (u16*)(ws + 151388160);      // 131072 B
    u16* Wol    = (u16*)(ws + 151519232);      // 131072 B
    float* out  = (float*)d_out;

    hipLaunchKernelGGL(prep, dim3(12544), dim3(256), 0, stream, msa, Wq, Wk, Wv, Wo,
                       msa_bf, Wqkv, Woh, Wol);
    hipLaunchKernelGGL(qkv_gemm, dim3(2304), dim3(256), 0, stream, msa_bf, Wqkv, Qb, Kb, VTb);
    hipLaunchKernelGGL(msa_attention, dim3(3072), dim3(256), 0, stream, Qb, Kb, VTb, Ahi);
    hipLaunchKernelGGL(out_gemm, dim3(768), dim3(256), 0, stream, Ahi, Woh, Wol, out);
}